// Round 4
// baseline (62.972 us; speedup 1.0000x reference)
//
#include <hip/hip_runtime.h>

// RBF layer: out[b,n] = exp(-GAMMA * (||x_b||^2 + ||w_n||^2 - 2 * x_b . w_n))
// x: (4096,256) fp32; W: (256,512) fp32; out: (4096,512) fp32.
// bf16 MFMA GEMM, 64x64 tile, both operands staged in LDS (bf16, padded rows).
// W transposed via 4x4 register transpose at stage time -> main loop is pure
// {ds_read_b128 + MFMA}. XCD-chunked swizzle: each XCD owns 8 by-tiles.

#define GAMMA 0.5f
#define B_  4096
#define D_  256
#define N_  512
#define BM  64
#define BN  64
#define LDT 264   // 256 + 8 pad (bf16): 528B row stride -> 4-bank row shift, b128-aligned

typedef __attribute__((ext_vector_type(8))) short bf16x8;
typedef __attribute__((ext_vector_type(4))) float f32x4;
typedef __attribute__((ext_vector_type(4))) unsigned short u16x4;
typedef __attribute__((ext_vector_type(4))) float float4v;

__device__ __forceinline__ unsigned short f2bf(float f) {
    union { float f; unsigned int i; } u; u.f = f;
    return (unsigned short)(u.i >> 16);
}
__device__ __forceinline__ float bf2f(unsigned short h) {
    union { unsigned int i; float f; } u; u.i = ((unsigned int)h) << 16;
    return u.f;
}

__global__ __launch_bounds__(256, 2)
void rbf_kernel(const float* __restrict__ x, const float* __restrict__ W,
                float* __restrict__ out) {
    __shared__ unsigned short xs[BM][LDT];   // x tile:  xs[b][k]
    __shared__ unsigned short ws[BN][LDT];   // W tile transposed: ws[n][k]
    __shared__ float x2s[BM];
    __shared__ float w2s[BN];

    const int tid = threadIdx.x;

    // XCD-chunked swizzle (512 % 8 == 0 -> bijective): XCD k gets by [8k,8k+8),
    // all 8 bx -> each x tile HBM-fetched once then L2-hit; W fully L2-hot.
    const int bid = blockIdx.x;
    const int wgid = (bid & 7) * 64 + (bid >> 3);
    const int bx = wgid & 7;    // 0..7
    const int by = wgid >> 3;   // 0..63

    // ---- stage x tile: 64x256 fp32 -> bf16 LDS (coalesced float4) ----
    {
        const float4v* xg = (const float4v*)(x + (size_t)by * BM * D_);
        #pragma unroll
        for (int t = 0; t < 16; ++t) {
            int i = tid + t * 256;
            int r = i >> 6, c4 = i & 63;
            float4v v = xg[i];
            u16x4 p = { f2bf(v.x), f2bf(v.y), f2bf(v.z), f2bf(v.w) };
            *(u16x4*)&xs[r][c4 * 4] = p;
        }
    }

    // ---- stage W transposed: 4x4 fp32 blocks, register transpose ----
    // block (kb,nb): rows k=4kb..4kb+3, cols n=4nb..4nb+3 (local). Lanes nb inner
    // -> global reads coalesce to 4x256B segments per instruction.
    {
        const float* Wg = W + bx * BN;
        #pragma unroll
        for (int t = 0; t < 4; ++t) {
            int i = tid + t * 256;           // 1024 blocks of 4x4
            int kb = i >> 4, nb = i & 15;
            const float* p0 = Wg + (size_t)(kb * 4) * N_ + nb * 4;
            float4v r0 = *(const float4v*)(p0);
            float4v r1 = *(const float4v*)(p0 + N_);
            float4v r2 = *(const float4v*)(p0 + 2 * N_);
            float4v r3 = *(const float4v*)(p0 + 3 * N_);
            u16x4 c0 = { f2bf(r0.x), f2bf(r1.x), f2bf(r2.x), f2bf(r3.x) };
            u16x4 c1 = { f2bf(r0.y), f2bf(r1.y), f2bf(r2.y), f2bf(r3.y) };
            u16x4 c2 = { f2bf(r0.z), f2bf(r1.z), f2bf(r2.z), f2bf(r3.z) };
            u16x4 c3 = { f2bf(r0.w), f2bf(r1.w), f2bf(r2.w), f2bf(r3.w) };
            *(u16x4*)&ws[nb * 4 + 0][kb * 4] = c0;
            *(u16x4*)&ws[nb * 4 + 1][kb * 4] = c1;
            *(u16x4*)&ws[nb * 4 + 2][kb * 4] = c2;
            *(u16x4*)&ws[nb * 4 + 3][kb * 4] = c3;
        }
    }
    __syncthreads();

    // ---- norms: one pass, 2 threads/row over 128 rows (waves 0-1: xs, 2-3: ws)
    {
        int row = tid >> 1, q = tid & 1;     // row 0..127
        const unsigned short* base = (row < BM) ? &xs[row][0] : &ws[row - BM][0];
        float s = 0.f;
        #pragma unroll
        for (int c = 0; c < 16; ++c) {
            bf16x8 v = *(const bf16x8*)&base[q * 128 + c * 8];
            #pragma unroll
            for (int j = 0; j < 8; ++j) { float f = bf2f((unsigned short)v[j]); s += f * f; }
        }
        s += __shfl_xor(s, 1);
        if (q == 0) {
            if (row < BM) x2s[row] = s; else w2s[row - BM] = s;
        }
    }
    __syncthreads();

    // ---- MFMA: 2x2 waves, each 32x32 sub-tile; pure LDS + MFMA ----
    const int l = tid & 63, w = tid >> 6;
    const int wr = w >> 1, wc = w & 1;
    const int lr = l & 15, g = l >> 4;

    f32x4 accs[2][2] = {{{0,0,0,0},{0,0,0,0}},{{0,0,0,0},{0,0,0,0}}};
    #pragma unroll
    for (int kk = 0; kk < 8; ++kk) {
        const int k0 = kk * 32 + g * 8;
        bf16x8 a0 = *(const bf16x8*)&xs[wr * 32 + lr][k0];
        bf16x8 a1 = *(const bf16x8*)&xs[wr * 32 + 16 + lr][k0];
        bf16x8 b0 = *(const bf16x8*)&ws[wc * 32 + lr][k0];
        bf16x8 b1 = *(const bf16x8*)&ws[wc * 32 + 16 + lr][k0];
        accs[0][0] = __builtin_amdgcn_mfma_f32_16x16x32_bf16(a0, b0, accs[0][0], 0, 0, 0);
        accs[0][1] = __builtin_amdgcn_mfma_f32_16x16x32_bf16(a0, b1, accs[0][1], 0, 0, 0);
        accs[1][0] = __builtin_amdgcn_mfma_f32_16x16x32_bf16(a1, b0, accs[1][0], 0, 0, 0);
        accs[1][1] = __builtin_amdgcn_mfma_f32_16x16x32_bf16(a1, b1, accs[1][1], 0, 0, 0);
    }

    // ---- epilogue: sq_dist -> exp2, fused, direct stores ----
    // C/D layout (m89/m91): col = lane&15, row = (lane>>4)*4 + i
    const float c2l = -(GAMMA) * 1.4426950408889634f;
    float* outp = out + (size_t)(by * BM) * N_ + bx * BN;
    #pragma unroll
    for (int m = 0; m < 2; ++m) {
        #pragma unroll
        for (int n = 0; n < 2; ++n) {
            int ac = wc * 32 + n * 16 + lr;
            float w2v = w2s[ac];
            #pragma unroll
            for (int i = 0; i < 4; ++i) {
                int ar = wr * 32 + m * 16 + g * 4 + i;
                float s = x2s[ar] + w2v - 2.f * accs[m][n][i];
                outp[(size_t)ar * N_ + ac] = exp2f(s * c2l);
            }
        }
    }
}

extern "C" void kernel_launch(void* const* d_in, const int* in_sizes, int n_in,
                              void* d_out, int out_size, void* d_ws, size_t ws_size,
                              hipStream_t stream) {
    const float* x = (const float*)d_in[0];
    const float* W = (const float*)d_in[1];
    float* out = (float*)d_out;
    rbf_kernel<<<dim3(512), dim3(256), 0, stream>>>(x, W, out);
}